// Round 1
// baseline (1326.335 us; speedup 1.0000x reference)
//
#include <hip/hip_runtime.h>
#include <hip/hip_fp16.h>

// FSRCNN fully fused: one block per image, whole pipeline in LDS.
// BS=1024, D=56, S=12, 32x32 -> 64x64, fp32 in/out; H + tail weights staged fp16.

#define TB 256
// ---- LDS float offsets (phase 1) ----
#define X_OFF     0        // 3*36*36 = 3888  (padded input, pad=2)
#define A_OFF     3888     // 12*34*34 = 13872 (padded, pad=1)
#define B_OFF     17760    // 12*34*34
#define WB_OFF    31632    // staged weights, up to 5272 floats
#define B6W_OFF   38000    // 672
#define B6B_OFF   38672    // 56
#define B6A_OFF   38728    // 56
#define TBI_OFF   38784    // 3 (tail bias)
#define LDS_FLOATS 38788
#define LDS_BYTES (LDS_FLOATS * 4)
// ---- phase 2 (half-precision regions, overlay X/A/B/WB which are dead) ----
// H: [56][32][38] halfs at half-index 0   (bytes 0..136191)
// WSUB: [3][56][5][9] halfs at half-index 68096 (bytes 136192..151311)

__global__ void __launch_bounds__(TB, 1)
fsrcnn_fused(const float* __restrict__ x,
             const float* __restrict__ head_w, const float* __restrict__ head_b, const float* __restrict__ head_a,
             const float* __restrict__ b0_w, const float* __restrict__ b0_b, const float* __restrict__ b0_a,
             const float* __restrict__ b1_w, const float* __restrict__ b1_b,
             const float* __restrict__ b2_w, const float* __restrict__ b2_b,
             const float* __restrict__ b3_w, const float* __restrict__ b3_b,
             const float* __restrict__ b4_w, const float* __restrict__ b4_b,
             const float* __restrict__ b5_a,
             const float* __restrict__ b6_w, const float* __restrict__ b6_b, const float* __restrict__ b6_a,
             const float* __restrict__ tail_w, const float* __restrict__ tail_b,
             float* __restrict__ out)
{
    extern __shared__ float lds[];
    const int tid = threadIdx.x;
    const int img = blockIdx.x;
    const int y   = tid >> 3;          // 0..31 : pixel row / tail u
    const int x0  = (tid & 7) << 2;    // 0..28 : pixel col base / tail v0

    // ---------------- stage padded x, zero A+B, stage head/b0 + b6/tail_b ----------------
    {
        const float* xg = x + img * 3072;
        for (int i = tid; i < 3888; i += TB) {
            const int c = i / 1296;
            const int rem = i - c * 1296;
            const int r = rem / 36;
            const int cl = rem - r * 36;
            const int iy = r - 2, ix = cl - 2;
            float v = 0.f;
            if ((unsigned)iy < 32u && (unsigned)ix < 32u)
                v = xg[(c << 10) + (iy << 5) + ix];
            lds[X_OFF + i] = v;
        }
        float4* ab = reinterpret_cast<float4*>(&lds[A_OFF]);
        const float4 z4 = make_float4(0.f, 0.f, 0.f, 0.f);
        for (int i = tid; i < 6936; i += TB) ab[i] = z4;   // zero A and B (borders stay 0)
        for (int i = tid; i < 5008; i += TB) {
            float v;
            if      (i < 4200) v = head_w[i];
            else if (i < 4256) v = head_b[i - 4200];
            else if (i < 4312) v = head_a[i - 4256];
            else if (i < 4984) v = b0_w[i - 4312];
            else if (i < 4996) v = b0_b[i - 4984];
            else               v = b0_a[i - 4996];
            lds[WB_OFF + i] = v;
        }
        for (int i = tid; i < 787; i += TB) {
            if      (i < 672) lds[B6W_OFF + i] = b6_w[i];
            else if (i < 728) lds[B6B_OFF + i - 672] = b6_b[i - 672];
            else if (i < 784) lds[B6A_OFF + i - 728] = b6_a[i - 728];
            else              lds[TBI_OFF + i - 784] = tail_b[i - 784];
        }
    }
    __syncthreads();

    // ---------------- head 5x5 3->56 pad2 + prelu + b0 1x1 56->12 + prelu -> A ----------------
    float accS[12][4];
    #pragma unroll
    for (int s = 0; s < 12; s++) {
        const float bb = lds[WB_OFF + 4984 + s];
        #pragma unroll
        for (int px = 0; px < 4; px++) accS[s][px] = bb;
    }
    for (int d0 = 0; d0 < 56; d0 += 4) {
        float ah[4][4];
        #pragma unroll
        for (int dd = 0; dd < 4; dd++) {
            const float hb = lds[WB_OFF + 4200 + d0 + dd];
            #pragma unroll
            for (int px = 0; px < 4; px++) ah[dd][px] = hb;
        }
        #pragma unroll
        for (int ci = 0; ci < 3; ci++) {
            #pragma unroll
            for (int ky = 0; ky < 5; ky++) {
                const float* xr = &lds[X_OFF + ci * 1296 + (y + ky) * 36 + x0];
                float xv[8];
                *reinterpret_cast<float4*>(&xv[0]) = *reinterpret_cast<const float4*>(xr);
                *reinterpret_cast<float4*>(&xv[4]) = *reinterpret_cast<const float4*>(xr + 4);
                #pragma unroll
                for (int dd = 0; dd < 4; dd++) {
                    const float* wr = &lds[WB_OFF + ((d0 + dd) * 3 + ci) * 25 + ky * 5];
                    #pragma unroll
                    for (int kx = 0; kx < 5; kx++) {
                        const float w = wr[kx];
                        #pragma unroll
                        for (int px = 0; px < 4; px++)
                            ah[dd][px] = fmaf(xv[px + kx], w, ah[dd][px]);
                    }
                }
            }
        }
        #pragma unroll
        for (int dd = 0; dd < 4; dd++) {
            const float al = lds[WB_OFF + 4256 + d0 + dd];
            float wv[12];
            #pragma unroll
            for (int s = 0; s < 12; s++) wv[s] = lds[WB_OFF + 4312 + s * 56 + d0 + dd];
            #pragma unroll
            for (int px = 0; px < 4; px++) {
                float v = ah[dd][px];
                v = (v >= 0.f) ? v : al * v;
                #pragma unroll
                for (int s = 0; s < 12; s++)
                    accS[s][px] = fmaf(wv[s], v, accS[s][px]);
            }
        }
    }
    #pragma unroll
    for (int s = 0; s < 12; s++) {
        const float al = lds[WB_OFF + 4996 + s];
        #pragma unroll
        for (int px = 0; px < 4; px++) {
            float v = accS[s][px];
            v = (v >= 0.f) ? v : al * v;
            lds[A_OFF + s * 1156 + (y + 1) * 34 + (x0 + 1 + px)] = v;
        }
    }
    __syncthreads();

    // ---------------- stage b1..b4 weights (+biases, b5_a) ----------------
    for (int i = tid; i < 5244; i += TB) {
        float v;
        if      (i < 1296) v = b1_w[i];
        else if (i < 1308) v = b1_b[i - 1296];
        else if (i < 2604) v = b2_w[i - 1308];
        else if (i < 2616) v = b2_b[i - 2604];
        else if (i < 3912) v = b3_w[i - 2616];
        else if (i < 3924) v = b3_b[i - 3912];
        else if (i < 5220) v = b4_w[i - 3924];
        else if (i < 5232) v = b4_b[i - 5220];
        else               v = b5_a[i - 5232];
        lds[WB_OFF + i] = v;
    }
    __syncthreads();

    // ---------------- b1..b3: 3x3 12->12 pad1, LDS->LDS ----------------
    auto conv3 = [&](int pofs, int qofs, int wofs, int bofs) {
        float acc[12][4];
        #pragma unroll
        for (int c = 0; c < 12; c++) {
            const float bb = lds[bofs + c];
            #pragma unroll
            for (int px = 0; px < 4; px++) acc[c][px] = bb;
        }
        for (int e = 0; e < 12; e++) {
            #pragma unroll
            for (int ky = 0; ky < 3; ky++) {
                const float* pr = &lds[pofs + e * 1156 + (y + ky) * 34 + x0];
                float xv[6];
                *reinterpret_cast<float2*>(&xv[0]) = *reinterpret_cast<const float2*>(pr);
                *reinterpret_cast<float2*>(&xv[2]) = *reinterpret_cast<const float2*>(pr + 2);
                *reinterpret_cast<float2*>(&xv[4]) = *reinterpret_cast<const float2*>(pr + 4);
                #pragma unroll
                for (int c = 0; c < 12; c++) {
                    const float* wr = &lds[wofs + (c * 12 + e) * 9 + ky * 3];
                    #pragma unroll
                    for (int kx = 0; kx < 3; kx++) {
                        const float w = wr[kx];
                        #pragma unroll
                        for (int px = 0; px < 4; px++)
                            acc[c][px] = fmaf(xv[px + kx], w, acc[c][px]);
                    }
                }
            }
        }
        #pragma unroll
        for (int c = 0; c < 12; c++)
            #pragma unroll
            for (int px = 0; px < 4; px++)
                lds[qofs + c * 1156 + (y + 1) * 34 + (x0 + 1 + px)] = acc[c][px];
        __syncthreads();
    };
    conv3(A_OFF, B_OFF, WB_OFF + 0,    WB_OFF + 1296);   // b1
    conv3(B_OFF, A_OFF, WB_OFF + 1308, WB_OFF + 2604);   // b2
    conv3(A_OFF, B_OFF, WB_OFF + 2616, WB_OFF + 3912);   // b3

    // ---------------- b4: 3x3 + prelu(b5_a) -> registers g ----------------
    float g[12][4];
    #pragma unroll
    for (int c = 0; c < 12; c++) {
        const float bb = lds[WB_OFF + 5220 + c];
        #pragma unroll
        for (int px = 0; px < 4; px++) g[c][px] = bb;
    }
    for (int e = 0; e < 12; e++) {
        #pragma unroll
        for (int ky = 0; ky < 3; ky++) {
            const float* pr = &lds[B_OFF + e * 1156 + (y + ky) * 34 + x0];
            float xv[6];
            *reinterpret_cast<float2*>(&xv[0]) = *reinterpret_cast<const float2*>(pr);
            *reinterpret_cast<float2*>(&xv[2]) = *reinterpret_cast<const float2*>(pr + 2);
            *reinterpret_cast<float2*>(&xv[4]) = *reinterpret_cast<const float2*>(pr + 4);
            #pragma unroll
            for (int c = 0; c < 12; c++) {
                const float* wr = &lds[WB_OFF + 3924 + (c * 12 + e) * 9 + ky * 3];
                #pragma unroll
                for (int kx = 0; kx < 3; kx++) {
                    const float w = wr[kx];
                    #pragma unroll
                    for (int px = 0; px < 4; px++)
                        g[c][px] = fmaf(xv[px + kx], w, g[c][px]);
                }
            }
        }
    }
    #pragma unroll
    for (int c = 0; c < 12; c++) {
        const float al = lds[WB_OFF + 5232 + c];
        #pragma unroll
        for (int px = 0; px < 4; px++) {
            const float v = g[c][px];
            g[c][px] = (v >= 0.f) ? v : al * v;
        }
    }
    __syncthreads();   // all reads of B / WB done -> safe to overlay with H

    // ---------------- b6 1x1 12->56 + prelu -> H fp16 [56][32][38] (col = ix+2) ----------------
    __half* Hp = reinterpret_cast<__half*>(lds);
    {
        for (int d = 0; d < 56; d++) {
            float wv[12];
            #pragma unroll
            for (int s = 0; s < 12; s++) wv[s] = lds[B6W_OFF + d * 12 + s];
            const float bb = lds[B6B_OFF + d];
            const float al = lds[B6A_OFF + d];
            float hv[4];
            #pragma unroll
            for (int px = 0; px < 4; px++) {
                float v = bb;
                #pragma unroll
                for (int s = 0; s < 12; s++) v = fmaf(wv[s], g[s][px], v);
                hv[px] = (v >= 0.f) ? v : al * v;
            }
            __half2* dst = reinterpret_cast<__half2*>(Hp + d * 1216 + y * 38 + (x0 + 2));
            dst[0] = __floats2half2_rn(hv[0], hv[1]);
            dst[1] = __floats2half2_rn(hv[2], hv[3]);
        }
        const __half2 zh = __floats2half2_rn(0.f, 0.f);
        for (int i = tid; i < 1792; i += TB) {          // zero pad cols 0,1 and 34,35
            const int d = i >> 5, r = i & 31;
            *reinterpret_cast<__half2*>(Hp + d * 1216 + r * 38)      = zh;
            *reinterpret_cast<__half2*>(Hp + d * 1216 + r * 38 + 34) = zh;
        }
    }
    __syncthreads();

    // ---------------- tail: 9x9 stride-2 convT 56->3, 2 passes over output-row parity ----------------
    __half* WS = reinterpret_cast<__half*>(lds) + 68096;   // [3][56][5][9]
    const float tb0 = lds[TBI_OFF + 0];
    const float tb1 = lds[TBI_OFF + 1];
    const float tb2 = lds[TBI_OFF + 2];
    #pragma unroll
    for (int ry = 0; ry < 2; ry++) {
        const int mcnt = 5 - ry;                 // ky = 2m+ry <= 8
        const int E = 3 * 56 * mcnt * 9;
        for (int i = tid; i < E; i += TB) {
            const int kx = i % 9;
            int t = i / 9;
            const int m = t % mcnt; t /= mcnt;
            const int d = t % 56;
            const int c = t / 56;
            WS[((c * 56 + d) * 5 + m) * 9 + kx] =
                __float2half(tail_w[(d * 3 + c) * 81 + (2 * m + ry) * 9 + kx]);
        }
        __syncthreads();
        float acc[3][8];
        #pragma unroll
        for (int q = 0; q < 8; q++) { acc[0][q] = tb0; acc[1][q] = tb1; acc[2][q] = tb2; }
        for (int d = 0; d < 56; d++) {
            const __half* wbase = WS + d * 45;
            #pragma unroll
            for (int m = 0; m < 5; m++) {
                if (m >= mcnt) continue;
                const int iy = y + 2 - m;        // oy = 2y+ry = 2*iy - 4 + (2m+ry)
                if ((unsigned)iy >= 32u) continue;
                const __half2* hp = reinterpret_cast<const __half2*>(Hp + d * 1216 + iy * 38 + x0);
                float xv[8];
                float2 f;
                f = __half22float2(hp[0]); xv[0] = f.x; xv[1] = f.y;
                f = __half22float2(hp[1]); xv[2] = f.x; xv[3] = f.y;
                f = __half22float2(hp[2]); xv[4] = f.x; xv[5] = f.y;
                f = __half22float2(hp[3]); xv[6] = f.x; xv[7] = f.y;
                #pragma unroll
                for (int kx = 0; kx < 9; kx++) {
                    const int n = kx >> 1, rx = kx & 1;  // kx = 2n+rx, ix = v+2-n
                    #pragma unroll
                    for (int c = 0; c < 3; c++) {
                        const float w = __half2float(wbase[c * 2520 + m * 9 + kx]);
                        #pragma unroll
                        for (int j = 0; j < 4; j++)
                            acc[c][2 * j + rx] = fmaf(xv[j + 4 - n], w, acc[c][2 * j + rx]);
                    }
                }
            }
        }
        const int oy = 2 * y + ry;
        float* op = out + (img * 3) * 4096 + oy * 64 + (x0 << 1);
        #pragma unroll
        for (int c = 0; c < 3; c++) {
            *reinterpret_cast<float4*>(op + c * 4096)     = make_float4(acc[c][0], acc[c][1], acc[c][2], acc[c][3]);
            *reinterpret_cast<float4*>(op + c * 4096 + 4) = make_float4(acc[c][4], acc[c][5], acc[c][6], acc[c][7]);
        }
        __syncthreads();
    }
}

extern "C" void kernel_launch(void* const* d_in, const int* in_sizes, int n_in,
                              void* d_out, int out_size, void* d_ws, size_t ws_size,
                              hipStream_t stream) {
    (void)in_sizes; (void)n_in; (void)d_ws; (void)ws_size; (void)out_size;
    const float* x      = (const float*)d_in[0];
    const float* head_w = (const float*)d_in[1];
    const float* head_b = (const float*)d_in[2];
    const float* head_a = (const float*)d_in[3];
    const float* b0_w   = (const float*)d_in[4];
    const float* b0_b   = (const float*)d_in[5];
    const float* b0_a   = (const float*)d_in[6];
    const float* b1_w   = (const float*)d_in[7];
    const float* b1_b   = (const float*)d_in[8];
    const float* b2_w   = (const float*)d_in[9];
    const float* b2_b   = (const float*)d_in[10];
    const float* b3_w   = (const float*)d_in[11];
    const float* b3_b   = (const float*)d_in[12];
    const float* b4_w   = (const float*)d_in[13];
    const float* b4_b   = (const float*)d_in[14];
    const float* b5_a   = (const float*)d_in[15];
    const float* b6_w   = (const float*)d_in[16];
    const float* b6_b   = (const float*)d_in[17];
    const float* b6_a   = (const float*)d_in[18];
    const float* tail_w = (const float*)d_in[19];
    const float* tail_b = (const float*)d_in[20];
    float* out = (float*)d_out;

    // idempotent; required for >64KB dynamic LDS (151.5 KB requested)
    hipFuncSetAttribute(reinterpret_cast<const void*>(fsrcnn_fused),
                        hipFuncAttributeMaxDynamicSharedMemorySize, LDS_BYTES);
    fsrcnn_fused<<<1024, TB, LDS_BYTES, stream>>>(
        x, head_w, head_b, head_a, b0_w, b0_b, b0_a,
        b1_w, b1_b, b2_w, b2_b, b3_w, b3_b, b4_w, b4_b, b5_a,
        b6_w, b6_b, b6_a, tail_w, tail_b, out);
}

// Round 2
// 944.892 us; speedup vs baseline: 1.4037x; 1.4037x over previous
//
#include <hip/hip_runtime.h>
#include <hip/hip_fp16.h>

// FSRCNN fully fused, one block per image. Round 2:
//  - TB=512 (8 waves/CU), 2 px/thread.
//  - ALL weights/biases/alphas read from GLOBAL with wave-uniform indices ->
//    scalar loads (s_load) on the scalar pipe; LDS holds only activations.
//  - Tail weights fp32 (no cvt); H fp16 [56][36][38] with zero frame (no branches).

#define TB 512
// ---- LDS float offsets (phase 1) ----
#define X_OFF 0        // 3*36*36 = 3888 floats (padded input, pad=2)
#define A_OFF 3888     // 12*34*34 = 13872 floats (padded, pad=1)
#define B_OFF 17760    // 12*34*34 ; phase-1 end = 31632 floats (126528 B)
// ---- phase 2: H fp16 [56][36][38], overlays everything ----
#define HSTR 38
#define HDSZ (36 * HSTR)            // 1368 halfs per channel
#define LDS_BYTES (56 * HDSZ * 2)   // 153216 B  (< 160 KiB)

__global__ void __launch_bounds__(TB, 2)
fsrcnn_fused(const float* __restrict__ x,
             const float* __restrict__ head_w, const float* __restrict__ head_b, const float* __restrict__ head_a,
             const float* __restrict__ b0_w, const float* __restrict__ b0_b, const float* __restrict__ b0_a,
             const float* __restrict__ b1_w, const float* __restrict__ b1_b,
             const float* __restrict__ b2_w, const float* __restrict__ b2_b,
             const float* __restrict__ b3_w, const float* __restrict__ b3_b,
             const float* __restrict__ b4_w, const float* __restrict__ b4_b,
             const float* __restrict__ b5_a,
             const float* __restrict__ b6_w, const float* __restrict__ b6_b, const float* __restrict__ b6_a,
             const float* __restrict__ tail_w, const float* __restrict__ tail_b,
             float* __restrict__ out)
{
    extern __shared__ float lds[];
    const int tid = threadIdx.x;
    const int img = blockIdx.x;
    const int y   = tid >> 4;          // 0..31 pixel row
    const int x0  = (tid & 15) << 1;   // 0..30 pixel col base (2 px/thread)

    // ---------------- stage padded x (3x36x36), zero A+B ----------------
    {
        const float* xg = x + img * 3072;
        for (int i = tid; i < 3888; i += TB) {
            const int c = i / 1296;
            const int rem = i - c * 1296;
            const int r = rem / 36;
            const int cl = rem - r * 36;
            const int iy = r - 2, ix = cl - 2;
            float v = 0.f;
            if ((unsigned)iy < 32u && (unsigned)ix < 32u)
                v = xg[(c << 10) + (iy << 5) + ix];
            lds[X_OFF + i] = v;
        }
        float4* ab = reinterpret_cast<float4*>(&lds[A_OFF]);
        const float4 z4 = make_float4(0.f, 0.f, 0.f, 0.f);
        for (int i = tid; i < 6936; i += TB) ab[i] = z4;   // zero A and B
    }
    __syncthreads();

    // ---------------- head 5x5 3->56 + prelu + b0 1x1 56->12 + prelu -> A ----------------
    float accS[12][2];
    #pragma unroll
    for (int s = 0; s < 12; s++) { const float bb = b0_b[s]; accS[s][0] = bb; accS[s][1] = bb; }
    for (int d0 = 0; d0 < 56; d0 += 4) {
        float ah[4][2];
        #pragma unroll
        for (int dd = 0; dd < 4; dd++) { const float hb = head_b[d0 + dd]; ah[dd][0] = hb; ah[dd][1] = hb; }
        #pragma unroll
        for (int ci = 0; ci < 3; ci++) {
            #pragma unroll
            for (int ky = 0; ky < 5; ky++) {
                const float* xr = &lds[X_OFF + ci * 1296 + (y + ky) * 36 + x0];
                float xv[6];
                *reinterpret_cast<float2*>(&xv[0]) = *reinterpret_cast<const float2*>(xr);
                *reinterpret_cast<float2*>(&xv[2]) = *reinterpret_cast<const float2*>(xr + 2);
                *reinterpret_cast<float2*>(&xv[4]) = *reinterpret_cast<const float2*>(xr + 4);
                #pragma unroll
                for (int dd = 0; dd < 4; dd++) {
                    const float* wr = &head_w[((d0 + dd) * 3 + ci) * 25 + ky * 5];
                    #pragma unroll
                    for (int kx = 0; kx < 5; kx++) {
                        const float w = wr[kx];                       // uniform -> s_load
                        ah[dd][0] = fmaf(xv[kx],     w, ah[dd][0]);
                        ah[dd][1] = fmaf(xv[kx + 1], w, ah[dd][1]);
                    }
                }
            }
        }
        #pragma unroll
        for (int dd = 0; dd < 4; dd++) {
            const float al = head_a[d0 + dd];
            float v0 = ah[dd][0]; v0 = (v0 >= 0.f) ? v0 : al * v0;
            float v1 = ah[dd][1]; v1 = (v1 >= 0.f) ? v1 : al * v1;
            #pragma unroll
            for (int s = 0; s < 12; s++) {
                const float w = b0_w[s * 56 + d0 + dd];               // uniform -> s_load
                accS[s][0] = fmaf(w, v0, accS[s][0]);
                accS[s][1] = fmaf(w, v1, accS[s][1]);
            }
        }
    }
    #pragma unroll
    for (int s = 0; s < 12; s++) {
        const float al = b0_a[s];
        float v0 = accS[s][0]; v0 = (v0 >= 0.f) ? v0 : al * v0;
        float v1 = accS[s][1]; v1 = (v1 >= 0.f) ? v1 : al * v1;
        lds[A_OFF + s * 1156 + (y + 1) * 34 + x0 + 1] = v0;
        lds[A_OFF + s * 1156 + (y + 1) * 34 + x0 + 2] = v1;
    }
    __syncthreads();

    // ---------------- b1..b3: 3x3 12->12 pad1, LDS->LDS, weights from global ----------------
    auto conv3 = [&](int pofs, int qofs, const float* __restrict__ w, const float* __restrict__ bias) {
        float acc[12][2];
        #pragma unroll
        for (int c = 0; c < 12; c++) { const float bb = bias[c]; acc[c][0] = bb; acc[c][1] = bb; }
        for (int e = 0; e < 12; e++) {
            #pragma unroll
            for (int ky = 0; ky < 3; ky++) {
                const float* pr = &lds[pofs + e * 1156 + (y + ky) * 34 + x0];
                float xv[4];
                *reinterpret_cast<float2*>(&xv[0]) = *reinterpret_cast<const float2*>(pr);
                *reinterpret_cast<float2*>(&xv[2]) = *reinterpret_cast<const float2*>(pr + 2);
                #pragma unroll
                for (int c = 0; c < 12; c++) {
                    const float* wr = &w[(c * 12 + e) * 9 + ky * 3];
                    #pragma unroll
                    for (int kx = 0; kx < 3; kx++) {
                        const float wv = wr[kx];                      // uniform -> s_load
                        acc[c][0] = fmaf(xv[kx],     wv, acc[c][0]);
                        acc[c][1] = fmaf(xv[kx + 1], wv, acc[c][1]);
                    }
                }
            }
        }
        #pragma unroll
        for (int c = 0; c < 12; c++) {
            lds[qofs + c * 1156 + (y + 1) * 34 + x0 + 1] = acc[c][0];
            lds[qofs + c * 1156 + (y + 1) * 34 + x0 + 2] = acc[c][1];
        }
        __syncthreads();
    };
    conv3(A_OFF, B_OFF, b1_w, b1_b);
    conv3(B_OFF, A_OFF, b2_w, b2_b);
    conv3(A_OFF, B_OFF, b3_w, b3_b);

    // ---------------- b4: 3x3 + prelu(b5_a) -> registers g ----------------
    float g[12][2];
    #pragma unroll
    for (int c = 0; c < 12; c++) { const float bb = b4_b[c]; g[c][0] = bb; g[c][1] = bb; }
    for (int e = 0; e < 12; e++) {
        #pragma unroll
        for (int ky = 0; ky < 3; ky++) {
            const float* pr = &lds[B_OFF + e * 1156 + (y + ky) * 34 + x0];
            float xv[4];
            *reinterpret_cast<float2*>(&xv[0]) = *reinterpret_cast<const float2*>(pr);
            *reinterpret_cast<float2*>(&xv[2]) = *reinterpret_cast<const float2*>(pr + 2);
            #pragma unroll
            for (int c = 0; c < 12; c++) {
                const float* wr = &b4_w[(c * 12 + e) * 9 + ky * 3];
                #pragma unroll
                for (int kx = 0; kx < 3; kx++) {
                    const float wv = wr[kx];
                    g[c][0] = fmaf(xv[kx],     wv, g[c][0]);
                    g[c][1] = fmaf(xv[kx + 1], wv, g[c][1]);
                }
            }
        }
    }
    #pragma unroll
    for (int c = 0; c < 12; c++) {
        const float al = b5_a[c];
        float v0 = g[c][0]; g[c][0] = (v0 >= 0.f) ? v0 : al * v0;
        float v1 = g[c][1]; g[c][1] = (v1 >= 0.f) ? v1 : al * v1;
    }
    __syncthreads();   // last reads of B done -> safe to overlay H

    // ---------------- b6 1x1 12->56 + prelu -> H fp16 [56][36][38] (+zero frame) ----------------
    __half* Hw = reinterpret_cast<__half*>(lds);
    {
        for (int d = 0; d < 56; d++) {
            float v0 = b6_b[d], v1 = v0;
            #pragma unroll
            for (int s = 0; s < 12; s++) {
                const float w = b6_w[d * 12 + s];                     // uniform -> s_load
                v0 = fmaf(w, g[s][0], v0);
                v1 = fmaf(w, g[s][1], v1);
            }
            const float al = b6_a[d];
            v0 = (v0 >= 0.f) ? v0 : al * v0;
            v1 = (v1 >= 0.f) ? v1 : al * v1;
            *reinterpret_cast<__half2*>(Hw + d * HDSZ + (y + 2) * HSTR + x0 + 2) =
                __floats2half2_rn(v0, v1);
        }
        const __half2 zh = __floats2half2_rn(0.f, 0.f);
        // top/bottom rows 0,1,34,35 (cols 0..35)
        for (int i = tid; i < 4032; i += TB) {
            const int d = i / 72;
            const int rem = i - d * 72;
            const int rr = rem / 18;
            const int cc = (rem - rr * 18) * 2;
            const int row = (rr & 1) + (rr >> 1) * 34;
            *reinterpret_cast<__half2*>(Hw + d * HDSZ + row * HSTR + cc) = zh;
        }
        // side cols 0,1 and 34,35 (rows 2..33)
        for (int i = tid; i < 3584; i += TB) {
            const int d = i >> 6;
            const int rem = i & 63;
            const int row = 2 + (rem >> 1);
            const int col = (rem & 1) * 34;
            *reinterpret_cast<__half2*>(Hw + d * HDSZ + row * HSTR + col) = zh;
        }
    }
    __syncthreads();

    // ---------------- tail: 9x9 stride-2 convT 56->3, weights fp32 from global ----------------
    const __half* Hp = reinterpret_cast<const __half*>(lds);
    const float tb0 = tail_b[0], tb1 = tail_b[1], tb2 = tail_b[2];
    #pragma unroll
    for (int ry = 0; ry < 2; ry++) {
        float acc[3][4];
        #pragma unroll
        for (int q = 0; q < 4; q++) { acc[0][q] = tb0; acc[1][q] = tb1; acc[2][q] = tb2; }
        #pragma unroll
        for (int m = 0; m < 5 - ry; m++) {         // ky = 2m+ry
            const int r = y + 4 - m;               // padded row index, always in [0,35]
            for (int d = 0; d < 56; d++) {
                const __half2* hp = reinterpret_cast<const __half2*>(Hp + d * HDSZ + r * HSTR + x0);
                float xv[6];
                float2 f;
                f = __half22float2(hp[0]); xv[0] = f.x; xv[1] = f.y;
                f = __half22float2(hp[1]); xv[2] = f.x; xv[3] = f.y;
                f = __half22float2(hp[2]); xv[4] = f.x; xv[5] = f.y;
                #pragma unroll
                for (int kx = 0; kx < 9; kx++) {
                    const int n = kx >> 1, rx = kx & 1;  // kx = 2n+rx, ix = v+2-n
                    #pragma unroll
                    for (int c = 0; c < 3; c++) {
                        const float w = tail_w[(d * 3 + c) * 81 + (2 * m + ry) * 9 + kx]; // uniform
                        acc[c][rx]     = fmaf(xv[4 - n], w, acc[c][rx]);
                        acc[c][2 + rx] = fmaf(xv[5 - n], w, acc[c][2 + rx]);
                    }
                }
            }
        }
        const int oy = 2 * y + ry;
        float* op = out + (img * 3) * 4096 + oy * 64 + (x0 << 1);
        #pragma unroll
        for (int c = 0; c < 3; c++)
            *reinterpret_cast<float4*>(op + c * 4096) =
                make_float4(acc[c][0], acc[c][1], acc[c][2], acc[c][3]);
    }
}

extern "C" void kernel_launch(void* const* d_in, const int* in_sizes, int n_in,
                              void* d_out, int out_size, void* d_ws, size_t ws_size,
                              hipStream_t stream) {
    (void)in_sizes; (void)n_in; (void)d_ws; (void)ws_size; (void)out_size;
    const float* x      = (const float*)d_in[0];
    const float* head_w = (const float*)d_in[1];
    const float* head_b = (const float*)d_in[2];
    const float* head_a = (const float*)d_in[3];
    const float* b0_w   = (const float*)d_in[4];
    const float* b0_b   = (const float*)d_in[5];
    const float* b0_a   = (const float*)d_in[6];
    const float* b1_w   = (const float*)d_in[7];
    const float* b1_b   = (const float*)d_in[8];
    const float* b2_w   = (const float*)d_in[9];
    const float* b2_b   = (const float*)d_in[10];
    const float* b3_w   = (const float*)d_in[11];
    const float* b3_b   = (const float*)d_in[12];
    const float* b4_w   = (const float*)d_in[13];
    const float* b4_b   = (const float*)d_in[14];
    const float* b5_a   = (const float*)d_in[15];
    const float* b6_w   = (const float*)d_in[16];
    const float* b6_b   = (const float*)d_in[17];
    const float* b6_a   = (const float*)d_in[18];
    const float* tail_w = (const float*)d_in[19];
    const float* tail_b = (const float*)d_in[20];
    float* out = (float*)d_out;

    hipFuncSetAttribute(reinterpret_cast<const void*>(fsrcnn_fused),
                        hipFuncAttributeMaxDynamicSharedMemorySize, LDS_BYTES);
    fsrcnn_fused<<<1024, TB, LDS_BYTES, stream>>>(
        x, head_w, head_b, head_a, b0_w, b0_b, b0_a,
        b1_w, b1_b, b2_w, b2_b, b3_w, b3_b, b4_w, b4_b, b5_a,
        b6_w, b6_b, b6_a, tail_w, tail_b, out);
}